// Round 5
// baseline (1030.587 us; speedup 1.0000x reference)
//
#include <hip/hip_runtime.h>

typedef _Float16 f16;
typedef __attribute__((ext_vector_type(8))) _Float16 f16x8;
typedef __attribute__((ext_vector_type(4))) _Float16 f16x4;
typedef __attribute__((ext_vector_type(2))) _Float16 f16x2;
typedef __attribute__((ext_vector_type(4))) float f32x4;

#define BKMAX 256
#define LDB   264   // 256 + 8 f16 pad: row stride 132 dwords -> 2-way bank aliasing (free)

// ---------------- narrow MFMA GEMM: 128x128 tile, whole-B-chunk in LDS (<=1 barrier pair
// per 256-K macro chunk), register-prefetched A. (ncols <= 128 paths)
__global__ __launch_bounds__(256) void gemm_mfma(
    const f16* __restrict__ A, int lda,
    const f16* __restrict__ Bt, int Kd,
    const float* __restrict__ bias,
    f16* __restrict__ Cb, float* __restrict__ Cf, int ldc,
    int R, int ncols, int relu,
    const float* __restrict__ scale_ptr)
{
    __shared__ f16 Bs[128 * LDB];   // 66 KB -> 2 blocks/CU
    const int tid  = threadIdx.x;
    const int wid  = tid >> 6;
    const int lane = tid & 63;
    const int m    = lane & 15;
    const int quad = lane >> 4;

    const long row0    = (long)blockIdx.x * 128 + wid * 32;
    const int  colbase = blockIdx.y * 128;

    f32x4 acc[2][8];
#pragma unroll
    for (int rt = 0; rt < 2; ++rt)
#pragma unroll
        for (int ct = 0; ct < 8; ++ct)
            acc[rt][ct] = f32x4{0.f, 0.f, 0.f, 0.f};

    const f16* Aptr[2];
#pragma unroll
    for (int rt = 0; rt < 2; ++rt) {
        long r = row0 + rt * 16 + m;
        if (r > (long)R - 1) r = (long)R - 1;
        Aptr[rt] = A + r * (long)lda + quad * 8;
    }

    f16x8 pa0 = *(const f16x8*)(Aptr[0]);
    f16x8 pa1 = *(const f16x8*)(Aptr[1]);

    const int  scol = tid >> 1;          // staging: 2 threads per col
    const int  shalf = (tid & 1) * 8;
    const long sbase = (long)(colbase + scol) * Kd;

    for (int k0 = 0; k0 < Kd; k0 += BKMAX) {
        const int BK = (Kd - k0 < BKMAX) ? (Kd - k0) : BKMAX;
        if (k0 != 0) __syncthreads();              // all waves done reading prev chunk
        for (int kc = shalf; kc < BK; kc += 16)
            *(f16x8*)&Bs[scol * LDB + kc] = *(const f16x8*)(Bt + sbase + k0 + kc);
        __syncthreads();
#pragma unroll 2
        for (int kk = 0; kk < BK; kk += 32) {
            f16x8 a0 = pa0, a1 = pa1;
            int kn = k0 + kk + 32;
            if (kn < Kd) {
                pa0 = *(const f16x8*)(Aptr[0] + kn);
                pa1 = *(const f16x8*)(Aptr[1] + kn);
            }
#pragma unroll
            for (int ct = 0; ct < 8; ++ct) {
                f16x8 b = *(const f16x8*)&Bs[(ct * 16 + m) * LDB + kk + quad * 8];
                acc[0][ct] = __builtin_amdgcn_mfma_f32_16x16x32_f16(a0, b, acc[0][ct], 0, 0, 0);
                acc[1][ct] = __builtin_amdgcn_mfma_f32_16x16x32_f16(a1, b, acc[1][ct], 0, 0, 0);
            }
        }
    }

    const float scale = scale_ptr ? *scale_ptr : 1.f;
#pragma unroll
    for (int ct = 0; ct < 8; ++ct) {
        int col = colbase + ct * 16 + m;
        if (col >= ncols) continue;
        float bv = bias ? bias[col] : 0.f;
#pragma unroll
        for (int rt = 0; rt < 2; ++rt) {
#pragma unroll
            for (int r = 0; r < 4; ++r) {
                long row = row0 + rt * 16 + quad * 4 + r;
                if (row < R) {
                    float v = acc[rt][ct][r] * scale + bv;
                    if (relu && v < 0.f) v = 0.f;
                    if (Cf) Cf[row * (long)ldc + col] = v;
                    else    Cb[row * (long)ldc + col] = (f16)v;
                }
            }
        }
    }
}

// ---------------- tall MFMA GEMM: 256x128 tile (4 waves x 64 rows), whole-B-chunk in LDS,
// optional fused column reductions: colsum (cols<200) and/or bn sum+sumsq.
__global__ __launch_bounds__(256, 2) void gemm_mfma_t(
    const f16* __restrict__ A, int lda,
    const f16* __restrict__ Bt, int Kd,
    const float* __restrict__ bias,
    f16* __restrict__ Cb, float* __restrict__ Cf, int ldc,
    int R, int ncols, int relu,
    const float* __restrict__ scale_ptr,
    float* __restrict__ colsum_ptr,
    float* __restrict__ bnsum_ptr)
{
    __shared__ f16 Bs[128 * LDB];   // 66 KB; reused as float scratch in reduction epilogue
    const int tid  = threadIdx.x;
    const int wid  = tid >> 6;
    const int lane = tid & 63;
    const int m    = lane & 15;
    const int quad = lane >> 4;

    const long row0    = (long)blockIdx.x * 256 + wid * 64;
    const int  colbase = blockIdx.y * 128;

    f32x4 acc[4][8];
#pragma unroll
    for (int rt = 0; rt < 4; ++rt)
#pragma unroll
        for (int ct = 0; ct < 8; ++ct)
            acc[rt][ct] = f32x4{0.f, 0.f, 0.f, 0.f};

    const f16* Aptr[4];
#pragma unroll
    for (int rt = 0; rt < 4; ++rt) {
        long r = row0 + rt * 16 + m;
        if (r > (long)R - 1) r = (long)R - 1;
        Aptr[rt] = A + r * (long)lda + quad * 8;
    }

    f16x8 pa[4];
#pragma unroll
    for (int rt = 0; rt < 4; ++rt) pa[rt] = *(const f16x8*)(Aptr[rt]);

    const int  scol = tid >> 1;
    const int  shalf = (tid & 1) * 8;
    const long sbase = (long)(colbase + scol) * Kd;

    for (int k0 = 0; k0 < Kd; k0 += BKMAX) {
        const int BK = (Kd - k0 < BKMAX) ? (Kd - k0) : BKMAX;
        if (k0 != 0) __syncthreads();
        for (int kc = shalf; kc < BK; kc += 16)
            *(f16x8*)&Bs[scol * LDB + kc] = *(const f16x8*)(Bt + sbase + k0 + kc);
        __syncthreads();
#pragma unroll 2
        for (int kk = 0; kk < BK; kk += 32) {
            f16x8 a[4];
#pragma unroll
            for (int rt = 0; rt < 4; ++rt) a[rt] = pa[rt];
            int kn = k0 + kk + 32;
            if (kn < Kd) {
#pragma unroll
                for (int rt = 0; rt < 4; ++rt) pa[rt] = *(const f16x8*)(Aptr[rt] + kn);
            }
#pragma unroll
            for (int ct = 0; ct < 8; ++ct) {
                f16x8 b = *(const f16x8*)&Bs[(ct * 16 + m) * LDB + kk + quad * 8];
#pragma unroll
                for (int rt = 0; rt < 4; ++rt)
                    acc[rt][ct] = __builtin_amdgcn_mfma_f32_16x16x32_f16(a[rt], b, acc[rt][ct], 0, 0, 0);
            }
        }
    }

    const float scale = scale_ptr ? *scale_ptr : 1.f;
    float rsum[8], rsq[8];
#pragma unroll
    for (int ct = 0; ct < 8; ++ct) { rsum[ct] = 0.f; rsq[ct] = 0.f; }

#pragma unroll
    for (int ct = 0; ct < 8; ++ct) {
        int col = colbase + ct * 16 + m;
        if (col >= ncols) continue;
        float bv = bias ? bias[col] : 0.f;
#pragma unroll
        for (int rt = 0; rt < 4; ++rt) {
#pragma unroll
            for (int r = 0; r < 4; ++r) {
                long row = row0 + rt * 16 + quad * 4 + r;
                if (row < R) {
                    float v = acc[rt][ct][r] * scale + bv;
                    if (relu && v < 0.f) v = 0.f;
                    if (Cf) Cf[row * (long)ldc + col] = v;
                    else    Cb[row * (long)ldc + col] = (f16)v;
                    rsum[ct] += v;
                    rsq[ct]  += v * v;
                }
            }
        }
    }

    if (colsum_ptr || bnsum_ptr) {
        __syncthreads();                  // all waves done reading Bs
        float* scr = (float*)Bs;          // plenty of space; use 1024 floats
#pragma unroll
        for (int ct = 0; ct < 8; ++ct) {
            float s = rsum[ct];
            s += __shfl_xor(s, 16);
            s += __shfl_xor(s, 32);
            float q = rsq[ct];
            q += __shfl_xor(q, 16);
            q += __shfl_xor(q, 32);
            if (quad == 0) {
                scr[wid * 128 + ct * 16 + m]       = s;
                scr[512 + wid * 128 + ct * 16 + m] = q;
            }
        }
        __syncthreads();
        if (tid < 128) {
            int col = colbase + tid;
            if (col < ncols) {
                float s = scr[tid] + scr[128 + tid] + scr[256 + tid] + scr[384 + tid];
                if (colsum_ptr && col < 200) atomicAdd(&colsum_ptr[col], s);
                if (bnsum_ptr) {
                    float q = scr[512 + tid] + scr[640 + tid] + scr[768 + tid] + scr[896 + tid];
                    atomicAdd(&bnsum_ptr[col], s);
                    atomicAdd(&bnsum_ptr[256 + col], q);
                }
            }
        }
    }
}

// ---------------- weight transpose + cast
__global__ void transpose_f2b(const float* __restrict__ in, int K, int ncols,
                              f16* __restrict__ out, int Kd, int npad)
{
    long idx = (long)blockIdx.x * 256 + threadIdx.x;
    long total = (long)npad * Kd;
    if (idx >= total) return;
    int k = (int)(idx % Kd);
    int n = (int)(idx / Kd);
    float v = (k < K && n < ncols) ? in[(long)k * ncols + n] : 0.f;
    out[idx] = (f16)v;
}

__global__ void cast_f2b(const float* __restrict__ in, long total, f16* __restrict__ out)
{
    long idx = (long)blockIdx.x * 256 + threadIdx.x;
    if (idx < total) out[idx] = (f16)in[idx];
}

// ---------------- CSR build: hist + 3-phase parallel scan + scatter
__global__ void hist_kernel(const int* __restrict__ dst, int E, int* __restrict__ cnt)
{
    int e = blockIdx.x * 256 + threadIdx.x;
    if (e < E) atomicAdd(&cnt[dst[e]], 1);
}

__global__ __launch_bounds__(1024) void scanA_kernel(const int* __restrict__ cnt, int n,
                                                     int* __restrict__ csum)
{
    __shared__ int sdata[1024];
    int t = threadIdx.x;
    int i = blockIdx.x * 1024 + t;
    sdata[t] = (i < n) ? cnt[i] : 0;
    __syncthreads();
    for (int d = 512; d > 0; d >>= 1) {
        if (t < d) sdata[t] += sdata[t + d];
        __syncthreads();
    }
    if (t == 0) csum[blockIdx.x] = sdata[0];
}

__global__ void scanB_kernel(int* __restrict__ csum, int nchunks, int n, int* __restrict__ rowptr)
{
    if (threadIdx.x == 0) {
        int run = 0;
        for (int b = 0; b < nchunks; ++b) {
            int v = csum[b];
            csum[b] = run;
            run += v;
        }
        rowptr[n] = run;
    }
}

__global__ __launch_bounds__(1024) void scanC_kernel(const int* __restrict__ cnt, int n,
                                                     const int* __restrict__ csum,
                                                     int* __restrict__ rowptr,
                                                     int* __restrict__ cursor,
                                                     float* __restrict__ dis)
{
    __shared__ int sdata[1024];
    int t = threadIdx.x;
    int i = blockIdx.x * 1024 + t;
    int v = (i < n) ? cnt[i] : 0;
    sdata[t] = v;
    __syncthreads();
    for (int d = 1; d < 1024; d <<= 1) {
        int x = (t >= d) ? sdata[t - d] : 0;
        __syncthreads();
        sdata[t] += x;
        __syncthreads();
    }
    if (i < n) {
        int excl = csum[blockIdx.x] + sdata[t] - v;
        rowptr[i] = excl;
        cursor[i] = excl;
        dis[i] = rsqrtf((float)(v + 1));   // deg = in-degree + self-loop
    }
}

__global__ void scatter_kernel(const int* __restrict__ src, const int* __restrict__ dst,
                               int E, int* __restrict__ cursor, int* __restrict__ colidx)
{
    int e = blockIdx.x * 256 + threadIdx.x;
    if (e < E) {
        int d = dst[e];
        int pos = atomicAdd(&cursor[d], 1);
        colidx[pos] = src[e];
    }
}

// ---------------- GCN aggregation: one wave per dst node, f16 h, 4x edge unroll
// (round-2 form: measured 61.5 us; r4's deeper pipeline regressed -> reverted)
__global__ __launch_bounds__(256) void agg_kernel(
    const f16* __restrict__ h, const int* __restrict__ rowptr,
    const int* __restrict__ colidx, const float* __restrict__ dis,
    const float* __restrict__ cb, f16* __restrict__ out, int ldc, int R)
{
    int wid = threadIdx.x >> 6, lane = threadIdx.x & 63;
    int i = blockIdx.x * 4 + wid;
    if (i >= R) return;
    float disi = dis[i];
    f16x4 hv = *(const f16x4*)(h + (long)i * 256 + lane * 4);
    float acc[4];
#pragma unroll
    for (int j = 0; j < 4; ++j) acc[j] = (float)hv[j] * disi;  // self loop
    int e0 = rowptr[i], e1 = rowptr[i + 1];
    int e = e0;
    for (; e + 3 < e1; e += 4) {
        int s0 = colidx[e], s1 = colidx[e + 1], s2 = colidx[e + 2], s3 = colidx[e + 3];
        float w0 = dis[s0], w1 = dis[s1], w2 = dis[s2], w3 = dis[s3];
        f16x4 h0 = *(const f16x4*)(h + (long)s0 * 256 + lane * 4);
        f16x4 h1 = *(const f16x4*)(h + (long)s1 * 256 + lane * 4);
        f16x4 h2 = *(const f16x4*)(h + (long)s2 * 256 + lane * 4);
        f16x4 h3 = *(const f16x4*)(h + (long)s3 * 256 + lane * 4);
#pragma unroll
        for (int j = 0; j < 4; ++j)
            acc[j] += (float)h0[j] * w0 + (float)h1[j] * w1
                    + (float)h2[j] * w2 + (float)h3[j] * w3;
    }
    for (; e < e1; ++e) {
        int s = colidx[e];
        float w = dis[s];
        f16x4 hs = *(const f16x4*)(h + (long)s * 256 + lane * 4);
#pragma unroll
        for (int j = 0; j < 4; ++j) acc[j] += (float)hs[j] * w;
    }
    f16x4 o;
#pragma unroll
    for (int j = 0; j < 4; ++j) {
        float v = acc[j] * disi + cb[lane * 4 + j];
        if (v < 0.f) v = 0.f;
        o[j] = (f16)v;
    }
    *(f16x4*)(out + (long)i * ldc + lane * 4) = o;
}

// nf from fused colsums; self-cleans csbuf for the next layer (saves a memset dispatch)
__global__ void nf_kernel(float* __restrict__ cs, float* __restrict__ scale, int R)
{
    __shared__ float s[128];
    int t = threadIdx.x;
    float v = 0.f;
    if (t < 100) {
        v = cs[t] * cs[100 + t];
        cs[t] = 0.f;            // each index read by exactly one thread -> safe
        cs[100 + t] = 0.f;
    }
    s[t] = v;
    __syncthreads();
    for (int d = 64; d > 0; d >>= 1) {
        if (t < d) s[t] += s[t + d];
        __syncthreads();
    }
    if (t == 0) scale[0] = 1.0f / (s[0] / (float)R + 1e-6f);
}

// ---------------- M = V^T Z via MFMA, two-stage, no atomics
#define VTZ_BLOCKS 192
__global__ __launch_bounds__(256) void vtz_mfma(const f16* __restrict__ t, int ld, int R,
                                                float* __restrict__ Mpart)
{
    __shared__ f16 Vt[112 * 72];
    __shared__ f16 Zt[112 * 72];
    const int tid  = threadIdx.x;
    const int wid  = tid >> 6;
    const int lane = tid & 63;
    const int m    = lane & 15;
    const int quad = lane >> 4;

    for (int idx = tid; idx < 12 * 64; idx += 256) {
        int c = 100 + (idx >> 6), r = idx & 63;
        Vt[c * 72 + r] = (f16)0.f;
        Zt[c * 72 + r] = (f16)0.f;
    }

    f32x4 acc[2][7];
#pragma unroll
    for (int rt = 0; rt < 2; ++rt)
#pragma unroll
        for (int ct = 0; ct < 7; ++ct)
            acc[rt][ct] = f32x4{0.f, 0.f, 0.f, 0.f};

    for (long base = (long)blockIdx.x * 64; base < R; base += (long)gridDim.x * 64) {
        __syncthreads();
        for (int idx = tid; idx < 50 * 64; idx += 256) {
            int r = idx / 50, c2 = (idx - r * 50) * 2;
            f16x2 v2 = f16x2{(f16)0.f, (f16)0.f};
            f16x2 z2 = f16x2{(f16)0.f, (f16)0.f};
            if (base + r < R) {
                v2 = *(const f16x2*)(t + (base + r) * ld + 100 + c2);
                z2 = *(const f16x2*)(t + (base + r) * ld + 200 + c2);
            }
            Vt[c2 * 72 + r] = v2[0]; Vt[(c2 + 1) * 72 + r] = v2[1];
            Zt[c2 * 72 + r] = z2[0]; Zt[(c2 + 1) * 72 + r] = z2[1];
        }
        __syncthreads();
#pragma unroll
        for (int ks = 0; ks < 2; ++ks) {
            int k0 = ks * 32 + quad * 8;
            f16x8 b[7];
#pragma unroll
            for (int ct = 0; ct < 7; ++ct)
                b[ct] = *(const f16x8*)&Zt[(ct * 16 + m) * 72 + k0];
#pragma unroll
            for (int rt = 0; rt < 2; ++rt) {
                int tr = wid + rt * 4;
                if (tr >= 7) continue;
                f16x8 a = *(const f16x8*)&Vt[(tr * 16 + m) * 72 + k0];
#pragma unroll
                for (int ct = 0; ct < 7; ++ct)
                    acc[rt][ct] = __builtin_amdgcn_mfma_f32_16x16x32_f16(a, b[ct], acc[rt][ct], 0, 0, 0);
            }
        }
    }

    float* out = Mpart + (long)blockIdx.x * 10000;
#pragma unroll
    for (int rt = 0; rt < 2; ++rt) {
        int tr = wid + rt * 4;
        if (tr >= 7) continue;
#pragma unroll
        for (int ct = 0; ct < 7; ++ct) {
            int b = ct * 16 + m;
            if (b >= 100) continue;
#pragma unroll
            for (int r = 0; r < 4; ++r) {
                int a = tr * 16 + quad * 4 + r;
                if (a < 100) out[a * 100 + b] = acc[rt][ct][r];
            }
        }
    }
}

// reduce Mpart, apply 1/nf scale (fp16-range protection: raw M entries can reach ~3e4),
// and emit MT = (M*scale)^T as f16 directly.
// MT zero-pad region (k>=100 or n>=100) is established once by an upfront memset.
__global__ void vtz_reduce2(const float* __restrict__ Mpart, f16* __restrict__ MT,
                            const float* __restrict__ scale_ptr)
{
    int idx = blockIdx.x * 256 + threadIdx.x;
    if (idx >= 10000) return;
    float s = 0.f;
    for (int b = 0; b < VTZ_BLOCKS; ++b) s += Mpart[(long)b * 10000 + idx];
    s *= *scale_ptr;
    int a = idx / 100, c = idx - a * 100;     // M[a][c]
    MT[c * 128 + a] = (f16)s;                 // MT[n*128+k] = M[k][n] * scale
}

// ---------------- batch norm finalize (stats fused into readout GEMM); self-cleans bnsum
__global__ void bn_finalize(float* __restrict__ sums, const float* __restrict__ g,
                            const float* __restrict__ bt, int R, float* __restrict__ ab)
{
    int c = threadIdx.x;
    float s0 = sums[c];
    float s1 = sums[256 + c];
    sums[c] = 0.f;              // ready for next layer's atomics
    sums[256 + c] = 0.f;
    float mean = s0 / (float)R;
    float var  = s1 / (float)R - mean * mean;
    if (var < 0.f) var = 0.f;
    float a = g[c] * rsqrtf(var + 1e-5f);
    ab[c] = a;
    ab[256 + c] = bt[c] - mean * a;
}

// ---------------- fold BN affine (x = y*a + b) into next layer's weights/biases:
//   x@cw = y@(diag(a)cw) + b@cw      -> scale cwT rows by a[k]; cb2[n] = sum_k b[k]*cw[k][n]
//   relu(x@aw+ab) = relu(y@(diag(a)aw) + ab2),  ab2[n] = ab0[n] + sum_k b[k]*aw[k][n]
__global__ __launch_bounds__(256) void bn_fold_all(
    f16* __restrict__ cwT, f16* __restrict__ awT,
    const float* __restrict__ cwf, const float* __restrict__ awf,
    const float* __restrict__ ab,          // a=ab[0..255], b=ab[256..511]
    const float* __restrict__ ab0,         // original abv for next layer (400)
    float* __restrict__ cb2, float* __restrict__ ab2)
{
    const int bid = blockIdx.x;
    const int t   = threadIdx.x;
    if (bid < 256) {
        int idx = bid * 256 + t;                       // [n][k], Kd=256
        cwT[idx] = (f16)((float)cwT[idx] * ab[idx & 255]);
    } else if (bid < 768) {
        int idx = (bid - 256) * 256 + t;               // 512 cols x 256 K (junk cols are 0)
        awT[idx] = (f16)((float)awT[idx] * ab[idx & 255]);
    } else if (bid == 768) {
        float s = 0.f;
        for (int k = 0; k < 256; ++k) s += ab[256 + k] * cwf[(long)k * 256 + t];
        cb2[t] = s;
    } else {
        int n = (bid - 769) * 256 + t;
        if (n < 400) {
            float s = ab0[n];
            for (int k = 0; k < 256; ++k) s += ab[256 + k] * awf[(long)k * 400 + n];
            ab2[n] = s;
        }
    }
}

// =====================================================================================
extern "C" void kernel_launch(void* const* d_in, const int* in_sizes, int n_in,
                              void* d_out, int out_size, void* d_ws, size_t ws_size,
                              hipStream_t stream)
{
    (void)n_in; (void)out_size; (void)ws_size;
    const int N = in_sizes[0] / 128;       // 50000
    const int E = in_sizes[1] / 2;         // 800000

    const float* x0 = (const float*)d_in[0];
    const int*  ei   = (const int*)d_in[1];
    const int*  esrc = ei;
    const int*  edst = ei + E;
    const float *cw[3], *cbv[3], *aw[3], *abv[3], *rw[3], *rbv[3];
    for (int l = 0; l < 3; ++l) {
        cw[l]  = (const float*)d_in[2 + 6 * l];
        cbv[l] = (const float*)d_in[3 + 6 * l];
        aw[l]  = (const float*)d_in[4 + 6 * l];
        abv[l] = (const float*)d_in[5 + 6 * l];
        rw[l]  = (const float*)d_in[6 + 6 * l];
        rbv[l] = (const float*)d_in[7 + 6 * l];
    }
    const float* g[2]   = {(const float*)d_in[20], (const float*)d_in[22]};
    const float* btb[2] = {(const float*)d_in[21], (const float*)d_in[23]};

    // ---- workspace carve ----
    char* p = (char*)d_ws;
    auto carve = [&](size_t bytes) -> char* {
        char* r = p; p += (bytes + 255) & ~(size_t)255; return r;
    };
    int*   cnt    = (int*)carve((size_t)N * 4);
    int*   rowptr = (int*)carve((size_t)(N + 1) * 4);
    int*   cursor = (int*)carve((size_t)N * 4);
    int*   colidx = (int*)carve((size_t)E * 4);
    float* dis    = (float*)carve((size_t)N * 4);
    int*   csum   = (int*)carve(256 * 4);
    float* Mpart  = (float*)carve((size_t)VTZ_BLOCKS * 10000 * 4);
    float* csbuf  = (float*)carve(200 * 4);
    float* scale  = (float*)carve(256);
    float* bnsum  = (float*)carve(512 * 4);
    float* bnab   = (float*)carve(512 * 4);
    float* cb2    = (float*)carve(256 * 4);
    float* ab2    = (float*)carve(400 * 4);
    f16*   MT     = (f16*)carve(128 * 128 * 2);
    f16*   cwT[3], *awT[3], *rwT[3];
    int din[3] = {128, 256, 256};
    int dou[3] = {256, 256, 128};
    for (int l = 0; l < 3; ++l) {
        cwT[l] = (f16*)carve((size_t)256 * din[l] * 2);
        awT[l] = (f16*)carve((size_t)512 * din[l] * 2);
        rwT[l] = (f16*)carve((size_t)dou[l] * 480 * 2);
    }
    f16*   xbf  = (f16*)carve((size_t)N * 256 * 2);         // current x (f16); holds pre-BN y for l>=1
    float* hbuf = (float*)carve((size_t)N * 256 * 4);       // hb (f16 h) aliases it
    f16*   hb   = (f16*)hbuf;
    f16*   tbuf = (f16*)carve((size_t)N * 300 * 2);         // U|V|Z (ld=300)
    f16*   xcat = (f16*)carve(((size_t)N * 456 + 32) * 2);  // [res|T|xloc], ld=456

    // ---- CSR build (parallel scan) ----
    const int nchunks = (N + 1023) / 1024;
    hipMemsetAsync(cnt, 0, (size_t)N * 4, stream);
    hist_kernel<<<(E + 255) / 256, 256, 0, stream>>>(edst, E, cnt);
    scanA_kernel<<<nchunks, 1024, 0, stream>>>(cnt, N, csum);
    scanB_kernel<<<1, 64, 0, stream>>>(csum, nchunks, N, rowptr);
    scanC_kernel<<<nchunks, 1024, 0, stream>>>(cnt, N, csum, rowptr, cursor, dis);
    scatter_kernel<<<(E + 255) / 256, 256, 0, stream>>>(esrc, edst, E, cursor, colidx);

    // ---- weight transposes + x0 cast + one-time accumulator/pad zeroing ----
    for (int l = 0; l < 3; ++l) {
        transpose_f2b<<<((long)256 * din[l] + 255) / 256, 256, 0, stream>>>(
            cw[l], din[l], 256, cwT[l], din[l], 256);
        transpose_f2b<<<((long)512 * din[l] + 255) / 256, 256, 0, stream>>>(
            aw[l], din[l], 400, awT[l], din[l], 512);
        transpose_f2b<<<((long)dou[l] * 480 + 255) / 256, 256, 0, stream>>>(
            rw[l], 456, dou[l], rwT[l], 480, dou[l]);
    }
    cast_f2b<<<((long)N * 128 + 255) / 256, 256, 0, stream>>>(x0, (long)N * 128, xbf);
    hipMemsetAsync(csbuf, 0, 200 * 4, stream);     // self-cleaned by nf_kernel afterward
    hipMemsetAsync(bnsum, 0, 512 * 4, stream);     // self-cleaned by bn_finalize afterward
    hipMemsetAsync(MT, 0, 128 * 128 * 2, stream);  // zero pad region; live region rewritten per layer

    int lda = 128;
    const unsigned gx  = (unsigned)((N + 127) / 128);   // 128-row tiles
    const unsigned gx2 = (unsigned)((N + 255) / 256);   // 256-row tiles

    for (int l = 0; l < 3; ++l) {
        const float* gemm1_bias = (l > 0) ? cb2 : nullptr;         // b@cw fold (pre-aggregation)
        const float* gemm2_bias = (l > 0) ? ab2 : abv[0];          // ab + b@aw fold
        const float* gemm3_bias = (l > 0) ? ab2 + 300 : abv[0] + 300;

        // 1) h = x @ cw (+ folded BN shift) -> hb (f16; cb/relu deferred to agg)  [tall tile]
        gemm_mfma_t<<<dim3(gx2, 2), 256, 0, stream>>>(xbf, lda, cwT[l], din[l], gemm1_bias,
                                                      hb, nullptr, 256, N, 256, 0, nullptr,
                                                      nullptr, nullptr);
        // 2) U|V|Z = relu(x @ aw[:,0:300] + bias) -> tbuf, fused colsum of cols<200
        gemm_mfma_t<<<dim3(gx2, 3), 256, 0, stream>>>(xbf, lda, awT[l], din[l], gemm2_bias,
                                                      tbuf, nullptr, 300, N, 300, 1, nullptr,
                                                      csbuf, nullptr);
        // 3) T = relu(x @ aw[:,300:400] + bias) -> xcat cols 100..199  [narrow]
        gemm_mfma<<<dim3(gx, 1), 256, 0, stream>>>(xbf, lda, awT[l] + (long)300 * din[l], din[l],
                                                   gemm3_bias,
                                                   xcat + 100, nullptr, 456, N, 100, 1, nullptr);
        // 4) nf from fused colsums (also re-zeroes csbuf)
        nf_kernel<<<1, 128, 0, stream>>>(csbuf, scale, N);
        // 5) M = V^T Z (MFMA two-stage); reduce applies 1/nf and writes MT (f16, transposed)
        vtz_mfma<<<VTZ_BLOCKS, 256, 0, stream>>>(tbuf, 300, N, Mpart);
        vtz_reduce2<<<40, 256, 0, stream>>>(Mpart, MT, scale);
        // 6) res = (U @ M_scaled) -> xcat cols 0..99  [narrow; scale pre-folded into MT]
        gemm_mfma<<<dim3(gx, 1), 256, 0, stream>>>(tbuf, 300, MT, 128, nullptr,
                                                   xcat, nullptr, 456, N, 100, 0, nullptr);
        // 7) x_local = relu(agg + cb) -> xcat cols 200..455
        agg_kernel<<<(N + 3) / 4, 256, 0, stream>>>(hb, rowptr, colidx, dis, cbv[l],
                                                    xcat + 200, 456, N);
        // 8) readout (Kd=480: cols 456..479 junk x zero weight rows = 0)
        if (l < 2) {
            // write pre-BN y directly as f16; BN stats fused (exact fp32 v); BN affine is
            // folded into next layer's weights by bn_fold_all -> no bn_apply pass.
            gemm_mfma_t<<<dim3(gx2, 2), 256, 0, stream>>>(xcat, 456, rwT[l], 480, rbv[l],
                                                          xbf, nullptr, 256, N, 256, 1, nullptr,
                                                          nullptr, bnsum);
            bn_finalize<<<1, 256, 0, stream>>>(bnsum, g[l], btb[l], N, bnab);
            bn_fold_all<<<771, 256, 0, stream>>>(cwT[l + 1], awT[l + 1], cw[l + 1], aw[l + 1],
                                                 bnab, abv[l + 1], cb2, ab2);
            lda = 256;
        } else {
            gemm_mfma<<<dim3(gx, 1), 256, 0, stream>>>(xcat, 456, rwT[l], 480, rbv[l],
                                                       nullptr, (float*)d_out, 128, N, 128, 0, nullptr);
        }
    }
}

// Round 6
// 957.600 us; speedup vs baseline: 1.0762x; 1.0762x over previous
//
#include <hip/hip_runtime.h>

typedef _Float16 f16;
typedef __attribute__((ext_vector_type(8))) _Float16 f16x8;
typedef __attribute__((ext_vector_type(4))) _Float16 f16x4;
typedef __attribute__((ext_vector_type(2))) _Float16 f16x2;
typedef __attribute__((ext_vector_type(4))) float f32x4;

#define BKMAX 256
#define LDB   264   // 256 + 8 f16 pad: row stride 132 dwords -> 2-way bank aliasing (free)

// ---------------- fused layer-front GEMM: [h | U|V|Z | T] = x @ [cw | aw] in one dispatch.
// 256x128 tiles (4 waves x 64 rows), whole-K B in LDS, epilogue routes by column range:
//   cols [0,256)   -> hb   (ldc 256, no relu)          bias = biascat[col]
//   cols [256,556) -> tbuf (ldc 300, relu, colsum on [256,456))
//   cols [556,656) -> xcatT (= xcat+100, ldc 456, relu)
//   cols >= 656    -> dropped (zero-padded B)
__global__ __launch_bounds__(256, 2) void gemm_fused3(
    const f16* __restrict__ A, int lda,
    const f16* __restrict__ Bt, int Kd,
    const float* __restrict__ biascat,
    f16* __restrict__ hb, f16* __restrict__ tbuf, f16* __restrict__ xcatT,
    int R, float* __restrict__ csbuf)
{
    __shared__ f16 Bs[128 * LDB];
    const int tid  = threadIdx.x;
    const int wid  = tid >> 6;
    const int lane = tid & 63;
    const int m    = lane & 15;
    const int quad = lane >> 4;

    const long row0    = (long)blockIdx.x * 256 + wid * 64;
    const int  colbase = blockIdx.y * 128;

    f32x4 acc[4][8];
#pragma unroll
    for (int rt = 0; rt < 4; ++rt)
#pragma unroll
        for (int ct = 0; ct < 8; ++ct)
            acc[rt][ct] = f32x4{0.f, 0.f, 0.f, 0.f};

    const f16* Aptr[4];
#pragma unroll
    for (int rt = 0; rt < 4; ++rt) {
        long r = row0 + rt * 16 + m;
        if (r > (long)R - 1) r = (long)R - 1;
        Aptr[rt] = A + r * (long)lda + quad * 8;
    }
    f16x8 pa[4];
#pragma unroll
    for (int rt = 0; rt < 4; ++rt) pa[rt] = *(const f16x8*)(Aptr[rt]);

    const int  scol  = tid >> 1;
    const int  shalf = (tid & 1) * 8;
    const long sbase = (long)(colbase + scol) * Kd;

    for (int k0 = 0; k0 < Kd; k0 += BKMAX) {
        const int BK = (Kd - k0 < BKMAX) ? (Kd - k0) : BKMAX;
        if (k0 != 0) __syncthreads();
        for (int kc = shalf; kc < BK; kc += 16)
            *(f16x8*)&Bs[scol * LDB + kc] = *(const f16x8*)(Bt + sbase + k0 + kc);
        __syncthreads();
#pragma unroll 2
        for (int kk = 0; kk < BK; kk += 32) {
            f16x8 a[4];
#pragma unroll
            for (int rt = 0; rt < 4; ++rt) a[rt] = pa[rt];
            int kn = k0 + kk + 32;
            if (kn < Kd) {
#pragma unroll
                for (int rt = 0; rt < 4; ++rt) pa[rt] = *(const f16x8*)(Aptr[rt] + kn);
            }
#pragma unroll
            for (int ct = 0; ct < 8; ++ct) {
                f16x8 b = *(const f16x8*)&Bs[(ct * 16 + m) * LDB + kk + quad * 8];
#pragma unroll
                for (int rt = 0; rt < 4; ++rt)
                    acc[rt][ct] = __builtin_amdgcn_mfma_f32_16x16x32_f16(a[rt], b, acc[rt][ct], 0, 0, 0);
            }
        }
    }

    float rsum[8];
#pragma unroll
    for (int ct = 0; ct < 8; ++ct) rsum[ct] = 0.f;

#pragma unroll
    for (int ct = 0; ct < 8; ++ct) {
        int col = colbase + ct * 16 + m;
        if (col >= 656) continue;
        float bv = biascat[col];
        bool isrelu = col >= 256;
        f16* dst; int ldc2, c2;
        if (col < 256)      { dst = hb;    ldc2 = 256; c2 = col; }
        else if (col < 556) { dst = tbuf;  ldc2 = 300; c2 = col - 256; }
        else                { dst = xcatT; ldc2 = 456; c2 = col - 556; }
#pragma unroll
        for (int rt = 0; rt < 4; ++rt) {
#pragma unroll
            for (int r = 0; r < 4; ++r) {
                long row = row0 + rt * 16 + quad * 4 + r;
                if (row < R) {
                    float v = acc[rt][ct][r] + bv;
                    if (isrelu && v < 0.f) v = 0.f;
                    dst[row * (long)ldc2 + c2] = (f16)v;
                    rsum[ct] += v;
                }
            }
        }
    }

    // fused colsum for U|V columns (global cols [256,456)) — only y-blocks 2,3
    if (colbase == 256 || colbase == 384) {
        __syncthreads();
        float* scr = (float*)Bs;
#pragma unroll
        for (int ct = 0; ct < 8; ++ct) {
            float s = rsum[ct];
            s += __shfl_xor(s, 16);
            s += __shfl_xor(s, 32);
            if (quad == 0) scr[wid * 128 + ct * 16 + m] = s;
        }
        __syncthreads();
        if (tid < 128) {
            int gcol = colbase + tid;
            if (gcol < 456) {
                float s = scr[tid] + scr[128 + tid] + scr[256 + tid] + scr[384 + tid];
                atomicAdd(&csbuf[gcol - 256], s);
            }
        }
    }
}

// ---------------- narrow MFMA GEMM: 128x128 tile, whole-B-chunk in LDS. (ncols <= 128)
__global__ __launch_bounds__(256) void gemm_mfma(
    const f16* __restrict__ A, int lda,
    const f16* __restrict__ Bt, int Kd,
    const float* __restrict__ bias,
    f16* __restrict__ Cb, float* __restrict__ Cf, int ldc,
    int R, int ncols, int relu,
    const float* __restrict__ scale_ptr)
{
    __shared__ f16 Bs[128 * LDB];
    const int tid  = threadIdx.x;
    const int wid  = tid >> 6;
    const int lane = tid & 63;
    const int m    = lane & 15;
    const int quad = lane >> 4;

    const long row0    = (long)blockIdx.x * 128 + wid * 32;
    const int  colbase = blockIdx.y * 128;

    f32x4 acc[2][8];
#pragma unroll
    for (int rt = 0; rt < 2; ++rt)
#pragma unroll
        for (int ct = 0; ct < 8; ++ct)
            acc[rt][ct] = f32x4{0.f, 0.f, 0.f, 0.f};

    const f16* Aptr[2];
#pragma unroll
    for (int rt = 0; rt < 2; ++rt) {
        long r = row0 + rt * 16 + m;
        if (r > (long)R - 1) r = (long)R - 1;
        Aptr[rt] = A + r * (long)lda + quad * 8;
    }
    f16x8 pa0 = *(const f16x8*)(Aptr[0]);
    f16x8 pa1 = *(const f16x8*)(Aptr[1]);

    const int  scol  = tid >> 1;
    const int  shalf = (tid & 1) * 8;
    const long sbase = (long)(colbase + scol) * Kd;

    for (int k0 = 0; k0 < Kd; k0 += BKMAX) {
        const int BK = (Kd - k0 < BKMAX) ? (Kd - k0) : BKMAX;
        if (k0 != 0) __syncthreads();
        for (int kc = shalf; kc < BK; kc += 16)
            *(f16x8*)&Bs[scol * LDB + kc] = *(const f16x8*)(Bt + sbase + k0 + kc);
        __syncthreads();
#pragma unroll 2
        for (int kk = 0; kk < BK; kk += 32) {
            f16x8 a0 = pa0, a1 = pa1;
            int kn = k0 + kk + 32;
            if (kn < Kd) {
                pa0 = *(const f16x8*)(Aptr[0] + kn);
                pa1 = *(const f16x8*)(Aptr[1] + kn);
            }
#pragma unroll
            for (int ct = 0; ct < 8; ++ct) {
                f16x8 b = *(const f16x8*)&Bs[(ct * 16 + m) * LDB + kk + quad * 8];
                acc[0][ct] = __builtin_amdgcn_mfma_f32_16x16x32_f16(a0, b, acc[0][ct], 0, 0, 0);
                acc[1][ct] = __builtin_amdgcn_mfma_f32_16x16x32_f16(a1, b, acc[1][ct], 0, 0, 0);
            }
        }
    }

    const float scale = scale_ptr ? *scale_ptr : 1.f;
#pragma unroll
    for (int ct = 0; ct < 8; ++ct) {
        int col = colbase + ct * 16 + m;
        if (col >= ncols) continue;
        float bv = bias ? bias[col] : 0.f;
#pragma unroll
        for (int rt = 0; rt < 2; ++rt) {
#pragma unroll
            for (int r = 0; r < 4; ++r) {
                long row = row0 + rt * 16 + quad * 4 + r;
                if (row < R) {
                    float v = acc[rt][ct][r] * scale + bv;
                    if (relu && v < 0.f) v = 0.f;
                    if (Cf) Cf[row * (long)ldc + col] = v;
                    else    Cb[row * (long)ldc + col] = (f16)v;
                }
            }
        }
    }
}

// ---------------- tall MFMA GEMM (readout): 256x128 tile, whole-B-chunk in LDS,
// fused bn sum+sumsq reduction.
__global__ __launch_bounds__(256, 2) void gemm_mfma_t(
    const f16* __restrict__ A, int lda,
    const f16* __restrict__ Bt, int Kd,
    const float* __restrict__ bias,
    f16* __restrict__ Cb, float* __restrict__ Cf, int ldc,
    int R, int ncols, int relu,
    float* __restrict__ bnsum_ptr)
{
    __shared__ f16 Bs[128 * LDB];
    const int tid  = threadIdx.x;
    const int wid  = tid >> 6;
    const int lane = tid & 63;
    const int m    = lane & 15;
    const int quad = lane >> 4;

    const long row0    = (long)blockIdx.x * 256 + wid * 64;
    const int  colbase = blockIdx.y * 128;

    f32x4 acc[4][8];
#pragma unroll
    for (int rt = 0; rt < 4; ++rt)
#pragma unroll
        for (int ct = 0; ct < 8; ++ct)
            acc[rt][ct] = f32x4{0.f, 0.f, 0.f, 0.f};

    const f16* Aptr[4];
#pragma unroll
    for (int rt = 0; rt < 4; ++rt) {
        long r = row0 + rt * 16 + m;
        if (r > (long)R - 1) r = (long)R - 1;
        Aptr[rt] = A + r * (long)lda + quad * 8;
    }
    f16x8 pa[4];
#pragma unroll
    for (int rt = 0; rt < 4; ++rt) pa[rt] = *(const f16x8*)(Aptr[rt]);

    const int  scol  = tid >> 1;
    const int  shalf = (tid & 1) * 8;
    const long sbase = (long)(colbase + scol) * Kd;

    for (int k0 = 0; k0 < Kd; k0 += BKMAX) {
        const int BK = (Kd - k0 < BKMAX) ? (Kd - k0) : BKMAX;
        if (k0 != 0) __syncthreads();
        for (int kc = shalf; kc < BK; kc += 16)
            *(f16x8*)&Bs[scol * LDB + kc] = *(const f16x8*)(Bt + sbase + k0 + kc);
        __syncthreads();
#pragma unroll 2
        for (int kk = 0; kk < BK; kk += 32) {
            f16x8 a[4];
#pragma unroll
            for (int rt = 0; rt < 4; ++rt) a[rt] = pa[rt];
            int kn = k0 + kk + 32;
            if (kn < Kd) {
#pragma unroll
                for (int rt = 0; rt < 4; ++rt) pa[rt] = *(const f16x8*)(Aptr[rt] + kn);
            }
#pragma unroll
            for (int ct = 0; ct < 8; ++ct) {
                f16x8 b = *(const f16x8*)&Bs[(ct * 16 + m) * LDB + kk + quad * 8];
#pragma unroll
                for (int rt = 0; rt < 4; ++rt)
                    acc[rt][ct] = __builtin_amdgcn_mfma_f32_16x16x32_f16(a[rt], b, acc[rt][ct], 0, 0, 0);
            }
        }
    }

    float rsum[8], rsq[8];
#pragma unroll
    for (int ct = 0; ct < 8; ++ct) { rsum[ct] = 0.f; rsq[ct] = 0.f; }

#pragma unroll
    for (int ct = 0; ct < 8; ++ct) {
        int col = colbase + ct * 16 + m;
        if (col >= ncols) continue;
        float bv = bias ? bias[col] : 0.f;
#pragma unroll
        for (int rt = 0; rt < 4; ++rt) {
#pragma unroll
            for (int r = 0; r < 4; ++r) {
                long row = row0 + rt * 16 + quad * 4 + r;
                if (row < R) {
                    float v = acc[rt][ct][r] + bv;
                    if (relu && v < 0.f) v = 0.f;
                    if (Cf) Cf[row * (long)ldc + col] = v;
                    else    Cb[row * (long)ldc + col] = (f16)v;
                    rsum[ct] += v;
                    rsq[ct]  += v * v;
                }
            }
        }
    }

    if (bnsum_ptr) {
        __syncthreads();
        float* scr = (float*)Bs;
#pragma unroll
        for (int ct = 0; ct < 8; ++ct) {
            float s = rsum[ct];
            s += __shfl_xor(s, 16);
            s += __shfl_xor(s, 32);
            float q = rsq[ct];
            q += __shfl_xor(q, 16);
            q += __shfl_xor(q, 32);
            if (quad == 0) {
                scr[wid * 128 + ct * 16 + m]       = s;
                scr[512 + wid * 128 + ct * 16 + m] = q;
            }
        }
        __syncthreads();
        if (tid < 128) {
            int col = colbase + tid;
            if (col < ncols) {
                float s = scr[tid] + scr[128 + tid] + scr[256 + tid] + scr[384 + tid];
                float q = scr[512 + tid] + scr[640 + tid] + scr[768 + tid] + scr[896 + tid];
                atomicAdd(&bnsum_ptr[col], s);
                atomicAdd(&bnsum_ptr[256 + col], q);
            }
        }
    }
}

// ---------------- one-shot prep: all weight transposes, x0 cast, zero-fills, biascat init
struct PrepJobs {
    const float* src[13];
    void*        dst[13];
    int   K[13], ncols[13], Kd[13], type[13];
    long  start[13], elems[13];
    int   njobs;
};

__global__ __launch_bounds__(256) void prep_all(PrepJobs J)
{
    long b = blockIdx.x;
    int j = 0;
    for (int i = 1; i < J.njobs; ++i)
        if (b >= J.start[i]) j = i;
    long idx = (b - J.start[j]) * 256 + threadIdx.x;
    if (idx >= J.elems[j]) return;
    int ty = J.type[j];
    if (ty == 0) {                       // transpose fp32[K][ncols] -> f16[idx/Kd][idx%Kd]
        int Kd = J.Kd[j];
        int k = (int)(idx % Kd);
        long n = idx / Kd;
        float v = (k < J.K[j] && n < J.ncols[j]) ? J.src[j][(long)k * J.ncols[j] + n] : 0.f;
        ((f16*)J.dst[j])[idx] = (f16)v;
    } else if (ty == 1) {                // cast fp32 -> f16
        ((f16*)J.dst[j])[idx] = (f16)J.src[j][idx];
    } else if (ty == 2) {                // zero floats
        ((float*)J.dst[j])[idx] = 0.f;
    } else {                             // biascat init: [0(256) | abv0(400) | 0(112)]
        float v = (idx >= 256 && idx < 656) ? J.src[j][idx - 256] : 0.f;
        ((float*)J.dst[j])[idx] = v;
    }
}

// ---------------- CSR build: hist + 3-phase parallel scan + scatter
__global__ void hist_kernel(const int* __restrict__ dst, int E, int* __restrict__ cnt)
{
    int e = blockIdx.x * 256 + threadIdx.x;
    if (e < E) atomicAdd(&cnt[dst[e]], 1);
}

__global__ __launch_bounds__(1024) void scanA_kernel(const int* __restrict__ cnt, int n,
                                                     int* __restrict__ csum)
{
    __shared__ int sdata[1024];
    int t = threadIdx.x;
    int i = blockIdx.x * 1024 + t;
    sdata[t] = (i < n) ? cnt[i] : 0;
    __syncthreads();
    for (int d = 512; d > 0; d >>= 1) {
        if (t < d) sdata[t] += sdata[t + d];
        __syncthreads();
    }
    if (t == 0) csum[blockIdx.x] = sdata[0];
}

__global__ void scanB_kernel(int* __restrict__ csum, int nchunks, int n, int* __restrict__ rowptr)
{
    if (threadIdx.x == 0) {
        int run = 0;
        for (int b = 0; b < nchunks; ++b) {
            int v = csum[b];
            csum[b] = run;
            run += v;
        }
        rowptr[n] = run;
    }
}

__global__ __launch_bounds__(1024) void scanC_kernel(const int* __restrict__ cnt, int n,
                                                     const int* __restrict__ csum,
                                                     int* __restrict__ rowptr,
                                                     int* __restrict__ cursor,
                                                     float* __restrict__ dis)
{
    __shared__ int sdata[1024];
    int t = threadIdx.x;
    int i = blockIdx.x * 1024 + t;
    int v = (i < n) ? cnt[i] : 0;
    sdata[t] = v;
    __syncthreads();
    for (int d = 1; d < 1024; d <<= 1) {
        int x = (t >= d) ? sdata[t - d] : 0;
        __syncthreads();
        sdata[t] += x;
        __syncthreads();
    }
    if (i < n) {
        int excl = csum[blockIdx.x] + sdata[t] - v;
        rowptr[i] = excl;
        cursor[i] = excl;
        dis[i] = rsqrtf((float)(v + 1));   // deg = in-degree + self-loop
    }
}

__global__ void scatter_kernel(const int* __restrict__ src, const int* __restrict__ dst,
                               int E, int* __restrict__ cursor, int* __restrict__ colidx)
{
    int e = blockIdx.x * 256 + threadIdx.x;
    if (e < E) {
        int d = dst[e];
        int pos = atomicAdd(&cursor[d], 1);
        colidx[pos] = src[e];
    }
}

// ---------------- GCN aggregation: one wave per dst node, f16 h, 4x edge unroll
// (round-2 form: measured 61.5 us)
__global__ __launch_bounds__(256) void agg_kernel(
    const f16* __restrict__ h, const int* __restrict__ rowptr,
    const int* __restrict__ colidx, const float* __restrict__ dis,
    const float* __restrict__ cb, f16* __restrict__ out, int ldc, int R)
{
    int wid = threadIdx.x >> 6, lane = threadIdx.x & 63;
    int i = blockIdx.x * 4 + wid;
    if (i >= R) return;
    float disi = dis[i];
    f16x4 hv = *(const f16x4*)(h + (long)i * 256 + lane * 4);
    float acc[4];
#pragma unroll
    for (int j = 0; j < 4; ++j) acc[j] = (float)hv[j] * disi;  // self loop
    int e0 = rowptr[i], e1 = rowptr[i + 1];
    int e = e0;
    for (; e + 3 < e1; e += 4) {
        int s0 = colidx[e], s1 = colidx[e + 1], s2 = colidx[e + 2], s3 = colidx[e + 3];
        float w0 = dis[s0], w1 = dis[s1], w2 = dis[s2], w3 = dis[s3];
        f16x4 h0 = *(const f16x4*)(h + (long)s0 * 256 + lane * 4);
        f16x4 h1 = *(const f16x4*)(h + (long)s1 * 256 + lane * 4);
        f16x4 h2 = *(const f16x4*)(h + (long)s2 * 256 + lane * 4);
        f16x4 h3 = *(const f16x4*)(h + (long)s3 * 256 + lane * 4);
#pragma unroll
        for (int j = 0; j < 4; ++j)
            acc[j] += (float)h0[j] * w0 + (float)h1[j] * w1
                    + (float)h2[j] * w2 + (float)h3[j] * w3;
    }
    for (; e < e1; ++e) {
        int s = colidx[e];
        float w = dis[s];
        f16x4 hs = *(const f16x4*)(h + (long)s * 256 + lane * 4);
#pragma unroll
        for (int j = 0; j < 4; ++j) acc[j] += (float)hs[j] * w;
    }
    f16x4 o;
#pragma unroll
    for (int j = 0; j < 4; ++j) {
        float v = acc[j] * disi + cb[lane * 4 + j];
        if (v < 0.f) v = 0.f;
        o[j] = (f16)v;
    }
    *(f16x4*)(out + (long)i * ldc + lane * 4) = o;
}

// ---------------- M = V^T Z via MFMA, two-stage, no atomics
#define VTZ_BLOCKS 192
__global__ __launch_bounds__(256) void vtz_mfma(const f16* __restrict__ t, int ld, int R,
                                                float* __restrict__ Mpart)
{
    __shared__ f16 Vt[112 * 72];
    __shared__ f16 Zt[112 * 72];
    const int tid  = threadIdx.x;
    const int wid  = tid >> 6;
    const int lane = tid & 63;
    const int m    = lane & 15;
    const int quad = lane >> 4;

    for (int idx = tid; idx < 12 * 64; idx += 256) {
        int c = 100 + (idx >> 6), r = idx & 63;
        Vt[c * 72 + r] = (f16)0.f;
        Zt[c * 72 + r] = (f16)0.f;
    }

    f32x4 acc[2][7];
#pragma unroll
    for (int rt = 0; rt < 2; ++rt)
#pragma unroll
        for (int ct = 0; ct < 7; ++ct)
            acc[rt][ct] = f32x4{0.f, 0.f, 0.f, 0.f};

    for (long base = (long)blockIdx.x * 64; base < R; base += (long)gridDim.x * 64) {
        __syncthreads();
        for (int idx = tid; idx < 50 * 64; idx += 256) {
            int r = idx / 50, c2 = (idx - r * 50) * 2;
            f16x2 v2 = f16x2{(f16)0.f, (f16)0.f};
            f16x2 z2 = f16x2{(f16)0.f, (f16)0.f};
            if (base + r < R) {
                v2 = *(const f16x2*)(t + (base + r) * ld + 100 + c2);
                z2 = *(const f16x2*)(t + (base + r) * ld + 200 + c2);
            }
            Vt[c2 * 72 + r] = v2[0]; Vt[(c2 + 1) * 72 + r] = v2[1];
            Zt[c2 * 72 + r] = z2[0]; Zt[(c2 + 1) * 72 + r] = z2[1];
        }
        __syncthreads();
#pragma unroll
        for (int ks = 0; ks < 2; ++ks) {
            int k0 = ks * 32 + quad * 8;
            f16x8 b[7];
#pragma unroll
            for (int ct = 0; ct < 7; ++ct)
                b[ct] = *(const f16x8*)&Zt[(ct * 16 + m) * 72 + k0];
#pragma unroll
            for (int rt = 0; rt < 2; ++rt) {
                int tr = wid + rt * 4;
                if (tr >= 7) continue;
                f16x8 a = *(const f16x8*)&Vt[(tr * 16 + m) * 72 + k0];
#pragma unroll
                for (int ct = 0; ct < 7; ++ct)
                    acc[rt][ct] = __builtin_amdgcn_mfma_f32_16x16x32_f16(a, b[ct], acc[rt][ct], 0, 0, 0);
            }
        }
    }

    float* out = Mpart + (long)blockIdx.x * 10000;
#pragma unroll
    for (int rt = 0; rt < 2; ++rt) {
        int tr = wid + rt * 4;
        if (tr >= 7) continue;
#pragma unroll
        for (int ct = 0; ct < 7; ++ct) {
            int b = ct * 16 + m;
            if (b >= 100) continue;
#pragma unroll
            for (int r = 0; r < 4; ++r) {
                int a = tr * 16 + quad * 4 + r;
                if (a < 100) out[a * 100 + b] = acc[rt][ct][r];
            }
        }
    }
}

// reduce Mpart; compute 1/nf scale inline from csbuf (each block redundantly — removes
// the separate nf dispatch); emit MT = (M*scale)^T as f16 (fp16-range protection).
__global__ __launch_bounds__(256) void vtz_reduce2(const float* __restrict__ Mpart,
                                                   f16* __restrict__ MT,
                                                   const float* __restrict__ cs, int R)
{
    __shared__ float s2[256];
    int t = threadIdx.x;
    float v = (t < 100) ? cs[t] * cs[100 + t] : 0.f;
    s2[t] = v;
    __syncthreads();
    for (int d = 128; d > 0; d >>= 1) {
        if (t < d) s2[t] += s2[t + d];
        __syncthreads();
    }
    float scale = 1.0f / (s2[0] / (float)R + 1e-6f);

    int idx = blockIdx.x * 256 + t;
    if (idx >= 10000) return;
    float s = 0.f;
    for (int b = 0; b < VTZ_BLOCKS; ++b) s += Mpart[(long)b * 10000 + idx];
    s *= scale;
    int a = idx / 100, c = idx - a * 100;     // M[a][c]
    MT[c * 128 + a] = (f16)s;                 // MT[n*128+k] = M[k][n] * scale
}

// ---------------- merged BN finalize + fold: each block recomputes the affine (a,b) from
// bnsum locally (LDS), then scales next layer's bigBT rows and rebuilds biascat.
//   blocks 0..767: bigBT[idx] *= a[idx&255]   (768 cols x 256 K)
//   block 768:     biascat[t]     = sum_k b[k]*cw[k][t]            (256 dots)
//   blocks 769,770: biascat[256+n] = ab0[n] + sum_k b[k]*aw[k][n]  (400 dots)
__global__ __launch_bounds__(256) void bn_fold2(
    f16* __restrict__ bigBT,
    const float* __restrict__ cwf, const float* __restrict__ awf,
    const float* __restrict__ bnsum, const float* __restrict__ g,
    const float* __restrict__ bt, int R,
    const float* __restrict__ ab0, float* __restrict__ biascat)
{
    __shared__ float a_s[256], b_s[256];
    const int t = threadIdx.x;
    {
        float s0 = bnsum[t];
        float s1 = bnsum[256 + t];
        float mean = s0 / (float)R;
        float var  = s1 / (float)R - mean * mean;
        if (var < 0.f) var = 0.f;
        float a = g[t] * rsqrtf(var + 1e-5f);
        a_s[t] = a;
        b_s[t] = bt[t] - mean * a;
    }
    __syncthreads();
    const int bid = blockIdx.x;
    if (bid < 768) {
        long idx = (long)bid * 256 + t;              // idx & 255 == t
        bigBT[idx] = (f16)((float)bigBT[idx] * a_s[t]);
    } else if (bid == 768) {
        float s = 0.f;
        for (int k = 0; k < 256; ++k) s += b_s[k] * cwf[(long)k * 256 + t];
        biascat[t] = s;
    } else {
        int n = (bid - 769) * 256 + t;
        if (n < 400) {
            float s = ab0[n];
            for (int k = 0; k < 256; ++k) s += b_s[k] * awf[(long)k * 400 + n];
            biascat[256 + n] = s;
        }
    }
}

// =====================================================================================
extern "C" void kernel_launch(void* const* d_in, const int* in_sizes, int n_in,
                              void* d_out, int out_size, void* d_ws, size_t ws_size,
                              hipStream_t stream)
{
    (void)n_in; (void)out_size; (void)ws_size;
    const int N = in_sizes[0] / 128;       // 50000
    const int E = in_sizes[1] / 2;         // 800000

    const float* x0 = (const float*)d_in[0];
    const int*  ei   = (const int*)d_in[1];
    const int*  esrc = ei;
    const int*  edst = ei + E;
    const float *cw[3], *cbv[3], *aw[3], *abv[3], *rw[3], *rbv[3];
    for (int l = 0; l < 3; ++l) {
        cw[l]  = (const float*)d_in[2 + 6 * l];
        cbv[l] = (const float*)d_in[3 + 6 * l];
        aw[l]  = (const float*)d_in[4 + 6 * l];
        abv[l] = (const float*)d_in[5 + 6 * l];
        rw[l]  = (const float*)d_in[6 + 6 * l];
        rbv[l] = (const float*)d_in[7 + 6 * l];
    }
    const float* g[2]   = {(const float*)d_in[20], (const float*)d_in[22]};
    const float* btb[2] = {(const float*)d_in[21], (const float*)d_in[23]};

    // ---- workspace carve ----
    char* p = (char*)d_ws;
    auto carve = [&](size_t bytes) -> char* {
        char* r = p; p += (bytes + 255) & ~(size_t)255; return r;
    };
    int*   cnt    = (int*)carve((size_t)N * 4);
    int*   rowptr = (int*)carve((size_t)(N + 1) * 4);
    int*   cursor = (int*)carve((size_t)N * 4);
    int*   colidx = (int*)carve((size_t)E * 4);
    float* dis    = (float*)carve((size_t)N * 4);
    int*   csum   = (int*)carve(256 * 4);
    float* Mpart  = (float*)carve((size_t)VTZ_BLOCKS * 10000 * 4);
    // zero region (one prep job zero-fills all of it): csbuf0/1/2, bnsumA/B, MT pad
    float* zr     = (float*)carve(9984 * 4);
    float* csbufL[3] = {zr, zr + 256, zr + 512};
    float* bnsumA = zr + 768;
    float* bnsumB = zr + 1280;
    f16*   MT     = (f16*)(zr + 1792);            // 16384 f16 = 8192 floats
    float* biascat = (float*)carve(768 * 4);
    f16*   bigBT[3], *rwT[3];
    int din[3] = {128, 256, 256};
    int dou[3] = {256, 256, 128};
    for (int l = 0; l < 3; ++l) {
        bigBT[l] = (f16*)carve((size_t)768 * din[l] * 2);
        rwT[l]   = (f16*)carve((size_t)dou[l] * 480 * 2);
    }
    f16*   xbf  = (f16*)carve((size_t)N * 256 * 2);         // current x (f16); pre-BN y for l>=1
    float* hbuf = (float*)carve((size_t)N * 256 * 4);       // hb (f16 h) aliases it
    f16*   hb   = (f16*)hbuf;
    f16*   tbuf = (f16*)carve((size_t)N * 300 * 2);         // U|V|Z (ld=300)
    f16*   xcat = (f16*)carve(((size_t)N * 456 + 32) * 2);  // [res|T|xloc], ld=456

    // ---- build prep job list ----
    PrepJobs J{};
    int nj = 0; long blk = 0;
    auto addJob = [&](const float* s, void* d, int K, int nc, int Kd, int ty, long elems) {
        J.src[nj] = s; J.dst[nj] = d; J.K[nj] = K; J.ncols[nj] = nc; J.Kd[nj] = Kd;
        J.type[nj] = ty; J.start[nj] = blk; J.elems[nj] = elems;
        blk += (elems + 255) / 256; ++nj;
    };
    for (int l = 0; l < 3; ++l)   // cw -> bigBT cols [0,256)
        addJob(cw[l], bigBT[l], din[l], 256, din[l], 0, (long)256 * din[l]);
    for (int l = 0; l < 3; ++l)   // aw -> bigBT cols [256,768), 400 real + zero pad
        addJob(aw[l], bigBT[l] + (long)256 * din[l], din[l], 400, din[l], 0, (long)512 * din[l]);
    for (int l = 0; l < 3; ++l)   // rw -> rwT
        addJob(rw[l], rwT[l], 456, dou[l], 480, 0, (long)dou[l] * 480);
    addJob(x0, xbf, 0, 0, 0, 1, (long)N * 128);   // cast
    addJob(nullptr, zr, 0, 0, 0, 2, 9984);        // zero csbufs/bnsums/MT
    addJob(nullptr, cnt, 0, 0, 0, 2, N);          // zero cnt (for hist)
    addJob(abv[0], biascat, 0, 0, 0, 3, 768);     // biascat init (layer 0)
    J.njobs = nj;

    prep_all<<<(unsigned)blk, 256, 0, stream>>>(J);

    // ---- CSR build ----
    const int nchunks = (N + 1023) / 1024;
    hist_kernel<<<(E + 255) / 256, 256, 0, stream>>>(edst, E, cnt);
    scanA_kernel<<<nchunks, 1024, 0, stream>>>(cnt, N, csum);
    scanB_kernel<<<1, 64, 0, stream>>>(csum, nchunks, N, rowptr);
    scanC_kernel<<<nchunks, 1024, 0, stream>>>(cnt, N, csum, rowptr, cursor, dis);
    scatter_kernel<<<(E + 255) / 256, 256, 0, stream>>>(esrc, edst, E, cursor, colidx);

    int lda = 128;
    const unsigned gx  = (unsigned)((N + 127) / 128);   // 128-row tiles
    const unsigned gx2 = (unsigned)((N + 255) / 256);   // 256-row tiles

    for (int l = 0; l < 3; ++l) {
        float* bnsumX = (l == 0) ? bnsumA : bnsumB;

        // 1) fused: [h | U|V|Z | T] = x @ [cw|aw] (+biascat), colsum fused
        gemm_fused3<<<dim3(gx2, 6), 256, 0, stream>>>(xbf, lda, bigBT[l], din[l], biascat,
                                                      hb, tbuf, xcat + 100, N, csbufL[l]);
        // 2) M = V^T Z; reduce computes 1/nf inline and writes MT (f16, transposed, scaled)
        vtz_mfma<<<VTZ_BLOCKS, 256, 0, stream>>>(tbuf, 300, N, Mpart);
        vtz_reduce2<<<40, 256, 0, stream>>>(Mpart, MT, csbufL[l], N);
        // 3) res = U @ M_scaled -> xcat cols 0..99
        gemm_mfma<<<dim3(gx, 1), 256, 0, stream>>>(tbuf, 300, MT, 128, nullptr,
                                                   xcat, nullptr, 456, N, 100, 0, nullptr);
        // 4) x_local = relu(agg + cb) -> xcat cols 200..455
        agg_kernel<<<(N + 3) / 4, 256, 0, stream>>>(hb, rowptr, colidx, dis, cbv[l],
                                                    xcat + 200, 456, N);
        // 5) readout
        if (l < 2) {
            gemm_mfma_t<<<dim3(gx2, 2), 256, 0, stream>>>(xcat, 456, rwT[l], 480, rbv[l],
                                                          xbf, nullptr, 256, N, 256, 1,
                                                          bnsumX);
            bn_fold2<<<771, 256, 0, stream>>>(bigBT[l + 1], cw[l + 1], aw[l + 1],
                                              bnsumX, g[l], btb[l], N,
                                              abv[l + 1], biascat);
            lda = 256;
        } else {
            gemm_mfma<<<dim3(gx, 1), 256, 0, stream>>>(xcat, 456, rwT[l], 480, rbv[l],
                                                       nullptr, (float*)d_out, 128, N, 128, 0, nullptr);
        }
    }
}